// Round 7
// baseline (785.130 us; speedup 1.0000x reference)
//
#include <hip/hip_runtime.h>
#include <math.h>

typedef __attribute__((ext_vector_type(8))) short bf16x8;
typedef __attribute__((ext_vector_type(4))) float f32x4;

namespace {
constexpr int NN = 2048;
constexpr float EPSV = 1e-5f;

// ---- workspace layout (bytes) ----
constexpr size_t WK_O   = 0;        // ushort[256*128]  Wk bf16 [o][c]
constexpr size_t WV_O   = 65536;    // ushort[256*128]  Wv bf16 [o][c]
constexpr size_t WEP_O  = 131072;   // ushort[256*256]  We bf16 [o][c]
constexpr size_t B1F_O  = 262144;   // float[1024]      folded bn bias for layer1
constexpr size_t WIMG_O = 266240;   // 32 pair-chunks x 32KB pre-swizzled [Wa1p 16KB | Wa2p 16KB]
constexpr size_t WP1Q_O = 1314816;  // float[64*4]      folded Wp1@Wq (+bias in .w)
constexpr size_t SC_O   = 1315840;  // float[1024]      attn bn scale

// ---- LDS layout (bytes) ----
constexpr int DBUF_OFF = 0;        // 2 x 32KB chunk-image double buffer
constexpr int SCW_OFF  = 65536;    // 4 waves x 2KB: key/X/val slices + hr
constexpr int PE_OFF   = 73728;    // 4 waves x 2KB: qpe'(1KB, -> b1f bias after epilogue) + pe(1KB)
constexpr int LDS_TOTAL = 81920;   // 80KB -> 2 blocks/CU exactly
}

__device__ __forceinline__ unsigned short f2bf(float x) {
    unsigned u = __float_as_uint(x);
    unsigned r = (u + 0x7FFFu + ((u >> 16) & 1u)) >> 16;
    return (unsigned short)r;
}
__device__ __forceinline__ float bf2f(unsigned short h) {
    return __uint_as_float(((unsigned)h) << 16);
}
__device__ __forceinline__ void gl_lds16(const void* gsrc, void* ldst) {
    __builtin_amdgcn_global_load_lds(
        (const __attribute__((address_space(1))) unsigned int*)gsrc,
        (__attribute__((address_space(3))) unsigned int*)ldst,
        16, 0, 0);
}

// ================= prep kernels =================

__global__ void prep_sc(const float* __restrict__ ag,  const float* __restrict__ ab,
                        const float* __restrict__ am,  const float* __restrict__ av,
                        const float* __restrict__ ba1,
                        const float* __restrict__ Wp1, const float* __restrict__ Wq,
                        const float* __restrict__ bq,  const float* __restrict__ bp1,
                        const float* __restrict__ pg,  const float* __restrict__ pb,
                        const float* __restrict__ pm,  const float* __restrict__ pv,
                        char* __restrict__ ws)
{
    const int t = threadIdx.x, blk = blockIdx.x;
    float* b1f  = (float*)(ws + B1F_O);
    float* sc_s = (float*)(ws + SC_O);
    float* wp1q = (float*)(ws + WP1Q_O);
    if (blk < 4) {
        int j = blk * 256 + t;
        float sc = ag[j] * rsqrtf(av[j] + EPSV);
        sc_s[j] = sc;
        b1f[j] = ba1[j] * sc + ab[j] - am[j] * sc;
    } else if (t < 64) {
        int ph = t;
        float scp = pg[ph] * rsqrtf(pv[ph] + EPSV);
        float a0 = 0.f, a1 = 0.f, a2 = 0.f, abv = 0.f;
        for (int c = 0; c < 256; ++c) {
            float wv = Wp1[ph * 256 + c];
            a0 = fmaf(wv, Wq[c * 3 + 0], a0);
            a1 = fmaf(wv, Wq[c * 3 + 1], a1);
            a2 = fmaf(wv, Wq[c * 3 + 2], a2);
            abv = fmaf(wv, bq[c], abv);
        }
        wp1q[ph * 4 + 0] = scp * a0;
        wp1q[ph * 4 + 1] = scp * a1;
        wp1q[ph * 4 + 2] = scp * a2;
        wp1q[ph * 4 + 3] = scp * (abv + bp1[ph]) + (pb[ph] - pm[ph] * scp);
    }
}

// bf16 conversions + pre-swizzled pair-chunk images; 640 blocks x 256
__global__ void prep_cvt(const float* __restrict__ Wk, const float* __restrict__ Wv,
                         const float* __restrict__ We, const float* __restrict__ Wa1,
                         const float* __restrict__ Wa2, char* __restrict__ ws)
{
    const int idx4 = blockIdx.x * 256 + threadIdx.x;
    if (idx4 >= 163840) return;
    const int e0 = idx4 * 4;
    const float* sc_s = (const float*)(ws + SC_O);

    if (e0 < 131072) {   // Wk | Wv | We linear bf16
        const float* src;
        unsigned short* dst;
        if (e0 < 32768)      { src = Wk + e0;          dst = (unsigned short*)(ws + WK_O)  + e0; }
        else if (e0 < 65536) { int e = e0 - 32768; src = Wv + e; dst = (unsigned short*)(ws + WV_O)  + e; }
        else                 { int e = e0 - 65536; src = We + e; dst = (unsigned short*)(ws + WEP_O) + e; }
        float4 v = *(const float4*)src;
        ushort4 o;
        o.x = f2bf(v.x); o.y = f2bf(v.y); o.z = f2bf(v.z); o.w = f2bf(v.w);
        *(ushort4*)dst = o;
    } else if (e0 < 393216) {   // Wa1 folded -> pair image [32j][256c] swz ^((jl&7)<<4)
        int e = e0 - 131072;
        int j = e >> 8, c = e & 255;
        float sc = sc_s[j];
        float4 v = *(const float4*)(Wa1 + e);
        int p = j >> 5, jl = j & 31;
        size_t byte = (size_t)p * 32768 + ((jl * 512 + c * 2) ^ ((jl & 7) << 4));
        ushort4 o;
        o.x = f2bf(v.x * sc); o.y = f2bf(v.y * sc); o.z = f2bf(v.z * sc); o.w = f2bf(v.w * sc);
        *(ushort4*)(ws + WIMG_O + byte) = o;
    } else {                    // Wa2 -> pair image, o-pair rows of 128B, swz ^(((o>>1)&7)<<4)
        int e = e0 - 393216;
        int o = e >> 10, j = e & 1023;
        float4 v = *(const float4*)(Wa2 + e);
        int p = j >> 5, jj = j & 31;
        size_t byte = (size_t)p * 32768 + 16384 +
                      (((o >> 1) * 128 + (o & 1) * 64 + jj * 2) ^ (((o >> 1) & 7) << 4));
        ushort4 ov;
        ov.x = f2bf(v.x); ov.y = f2bf(v.y); ov.z = f2bf(v.z); ov.w = f2bf(v.w);
        *(ushort4*)(ws + WIMG_O + byte) = ov;
    }
}

// ================= main fused kernel =================
// 1024 blocks (4 b x 256 n-tiles of 8), 256 threads = 4 waves; wave owns 32 rows (2 n).
// NOTE: __launch_bounds__ second arg MUST be 1 on this compiler: arg 2 caps VGPR at 128
// and spills the 128-reg Y accumulator to scratch (~1GB WRITE_SIZE, rounds 4-6).
__global__ __launch_bounds__(256, 1)
void pt_main(const float* __restrict__ key, const float* __restrict__ values,
             const float* __restrict__ pos,
             const float* __restrict__ Wq,  const float* __restrict__ bq,
             const float* __restrict__ bk,  const float* __restrict__ bv,
             const float* __restrict__ Wp2, const float* __restrict__ bp2,
             const float* __restrict__ be,
             const char* __restrict__ ws,
             float* __restrict__ outp)
{
    extern __shared__ char sm[];
    const int t = threadIdx.x;
    const int w = t >> 6, l = t & 63;
    const int l15 = l & 15, lg = l >> 4;
    // XCD-aware swizzle (1024 % 8 == 0 -> simple form is bijective)
    const int wg = (blockIdx.x & 7) * 128 + (blockIdx.x >> 3);
    const int b = wg >> 8;
    const int n0 = (wg & 255) * 8;

    char* scw = sm + SCW_OFF + w * 2048;
    char* pew = sm + PE_OFF + w * 2048;

    const unsigned short* wkp = (const unsigned short*)(ws + WK_O);
    const unsigned short* wvp = (const unsigned short*)(ws + WV_O);
    const unsigned short* wep = (const unsigned short*)(ws + WEP_O);
    const float* b1fp = (const float*)(ws + B1F_O);
    const float* wp1q = (const float*)(ws + WP1Q_O);
    const char* wimg = ws + WIMG_O;

    const f32x4 zf = {0.f, 0.f, 0.f, 0.f};

    // ---- prologue: stage pair-chunks 0 and 1 (land during the whole pre-phase) ----
    #pragma unroll
    for (int i = 0; i < 8; ++i)
        gl_lds16(wimg + i * 4096 + t * 16, sm + DBUF_OFF + i * 4096 + t * 16);
    #pragma unroll
    for (int i = 0; i < 8; ++i)
        gl_lds16(wimg + 32768 + i * 4096 + t * 16, sm + DBUF_OFF + 32768 + i * 4096 + t * 16);

    // ---- pe / qpe' phase (wave-local; nl = 2w + {0,1}) ----
    float p_[2][3];
    {
        const float4 wq4 = *(const float4*)(wp1q + l * 4);
        float h1v[2];
        #pragma unroll
        for (int nl = 0; nl < 2; ++nl) {
            int n = n0 + 2 * w + nl;
            p_[nl][0] = pos[(b * 3 + 0) * NN + n];
            p_[nl][1] = pos[(b * 3 + 1) * NN + n];
            p_[nl][2] = pos[(b * 3 + 2) * NN + n];
            h1v[nl] = fmaxf(fmaf(wq4.x, p_[nl][0],
                            fmaf(wq4.y, p_[nl][1],
                            fmaf(wq4.z, p_[nl][2], wq4.w))), 0.f);
        }
        float pacc[2][4];
        #pragma unroll
        for (int nl = 0; nl < 2; ++nl)
            #pragma unroll
            for (int oi = 0; oi < 4; ++oi) pacc[nl][oi] = 0.f;
        #pragma unroll 4
        for (int j4 = 0; j4 < 16; ++j4) {
            float h0[4], h1[4];
            #pragma unroll
            for (int jj = 0; jj < 4; ++jj) {
                h0[jj] = __shfl(h1v[0], j4 * 4 + jj);
                h1[jj] = __shfl(h1v[1], j4 * 4 + jj);
            }
            #pragma unroll
            for (int oi = 0; oi < 4; ++oi) {
                const float4 wv4 = *(const float4*)(Wp2 + (oi * 64 + l) * 64 + j4 * 4);
                pacc[0][oi] = fmaf(wv4.x, h0[0], fmaf(wv4.y, h0[1], fmaf(wv4.z, h0[2], fmaf(wv4.w, h0[3], pacc[0][oi]))));
                pacc[1][oi] = fmaf(wv4.x, h1[0], fmaf(wv4.y, h1[1], fmaf(wv4.z, h1[2], fmaf(wv4.w, h1[3], pacc[1][oi]))));
            }
        }
        #pragma unroll
        for (int oi = 0; oi < 4; ++oi) {
            int o = oi * 64 + l;
            float bp = bp2[o], bko = bk[o], bqo = bq[o];
            float wq0 = Wq[o * 3 + 0], wq1 = Wq[o * 3 + 1], wq2 = Wq[o * 3 + 2];
            #pragma unroll
            for (int nl = 0; nl < 2; ++nl) {
                float pe = pacc[nl][oi] + bp;
                float q  = fmaf(wq0, p_[nl][0], fmaf(wq1, p_[nl][1], fmaf(wq2, p_[nl][2], bqo)));
                *(unsigned short*)(pew + nl * 512 + o * 2)        = f2bf((q + 1.f - bko) * pe);
                *(unsigned short*)(pew + 1024 + nl * 512 + o * 2) = f2bf(pe);
            }
        }
    }

    // ---- kf GEMM in 4 c-slices of 32 through 2KB wave-private scratch ----
    const int kq = l & 3, nv = (l >> 2) & 1, c0 = l >> 3;
    f32x4 kacc[2][16];
    #pragma unroll
    for (int mt = 0; mt < 2; ++mt)
        #pragma unroll
        for (int ot = 0; ot < 16; ++ot) kacc[mt][ot] = zf;

    #pragma unroll 1
    for (int s = 0; s < 4; ++s) {
        const float* kb = key + ((size_t)b * 128 * NN + (size_t)(n0 + 2 * w + nv)) * 16 + kq * 4;
        #pragma unroll
        for (int i = 0; i < 4; ++i) {
            int c = s * 32 + i * 8 + c0;
            float4 v = *(const float4*)(kb + (size_t)c * NN * 16);
            int cl = i * 8 + c0;
            #pragma unroll
            for (int j = 0; j < 4; ++j) {
                int m = nv * 16 + kq * 4 + j;
                float fj = (j == 0) ? v.x : (j == 1) ? v.y : (j == 2) ? v.z : v.w;
                *(unsigned short*)(scw + (((m >> 1) * 128 + (m & 1) * 64 + cl * 2) ^ (((m >> 1) & 7) << 4))) = f2bf(fj);
            }
        }
        bf16x8 kB[2];
        #pragma unroll
        for (int mt = 0; mt < 2; ++mt) {
            int m = mt * 16 + l15;
            kB[mt] = *(const bf16x8*)(scw + (((m >> 1) * 128 + (m & 1) * 64 + lg * 16) ^ (((m >> 1) & 7) << 4)));
        }
        #pragma unroll 4
        for (int ot = 0; ot < 16; ++ot) {
            bf16x8 aW = *(const bf16x8*)(wkp + (ot * 16 + l15) * 128 + s * 32 + lg * 8);
            kacc[0][ot] = __builtin_amdgcn_mfma_f32_16x16x32_bf16(aW, kB[0], kacc[0][ot], 0, 0, 0);
            kacc[1][ot] = __builtin_amdgcn_mfma_f32_16x16x32_bf16(aW, kB[1], kacc[1][ot], 0, 0, 0);
        }
    }

    // ---- X epilogue -> ax registers, 8 o-slices of 32 through scratch ----
    bf16x8 ax[2][8];
    #pragma unroll 1
    for (int x = 0; x < 8; ++x) {
        #pragma unroll
        for (int mt = 0; mt < 2; ++mt) {
            const int m = mt * 16 + l15;
            #pragma unroll
            for (int oi = 0; oi < 2; ++oi) {
                int ot = x * 2 + oi;
                int o0 = ot * 16 + lg * 4;
                ushort4 qv  = *(const ushort4*)(pew + mt * 512 + o0 * 2);
                ushort4 pv4 = *(const ushort4*)(pew + 1024 + mt * 512 + o0 * 2);
                ushort4 pk;
                pk.x = f2bf(bf2f(qv.x) - kacc[mt][ot][0] * bf2f(pv4.x));
                pk.y = f2bf(bf2f(qv.y) - kacc[mt][ot][1] * bf2f(pv4.y));
                pk.z = f2bf(bf2f(qv.z) - kacc[mt][ot][2] * bf2f(pv4.z));
                pk.w = f2bf(bf2f(qv.w) - kacc[mt][ot][3] * bf2f(pv4.w));
                int ol = oi * 16 + lg * 4;
                *(ushort4*)(scw + (((m >> 1) * 128 + (m & 1) * 64 + ol * 2) ^ (((m >> 1) & 7) << 4))) = pk;
            }
        }
        #pragma unroll
        for (int mt = 0; mt < 2; ++mt) {
            int m = mt * 16 + l15;
            ax[mt][x] = *(const bf16x8*)(scw + (((m >> 1) * 128 + (m & 1) * 64 + lg * 16) ^ (((m >> 1) & 7) << 4)));
        }
    }

    // ---- qpe' rows are now dead: fill the 4x1KB holes with b1f (wave-local write) ----
    // hole layout: b1f[j] at sm + PE_OFF + (j>>8)*2048 + (j&255)*4
    *(float4*)(pew + l * 16) = *(const float4*)(b1fp + w * 256 + l * 4);

    // ---- attn MLP: 32 pair-chunks of 32 j; double-buffered gl_lds, counted vmcnt ----
    f32x4 Y[2][16];
    #pragma unroll
    for (int mt = 0; mt < 2; ++mt)
        #pragma unroll
        for (int ot = 0; ot < 16; ++ot) Y[mt][ot] = zf;

    char* hrb = scw;  // wave-private hr [32m][32j] bf16, pair-rows 128B, swz

    #pragma unroll 1
    for (int p = 0; p < 32; ++p) {
        if (p < 31) asm volatile("s_waitcnt vmcnt(8)" ::: "memory");   // stage(p) done, stage(p+1) in flight
        else        asm volatile("s_waitcnt vmcnt(0)" ::: "memory");
        __builtin_amdgcn_s_barrier();          // image p ready for all waves (b1f holes too, at p=0)
        __builtin_amdgcn_sched_barrier(0);

        const char* buf = sm + DBUF_OFF + (p & 1) * 32768;

        // layer1: C[j][m] = Wa1p @ X   (A = Wa1 rows j, B = ax cols m)
        __builtin_amdgcn_s_setprio(1);
        #pragma unroll
        for (int jt = 0; jt < 2; ++jt) {
            const int jl = jt * 16 + l15;
            f32x4 c1[2];
            c1[0] = zf; c1[1] = zf;
            #pragma unroll
            for (int kt = 0; kt < 8; ++kt) {
                bf16x8 aw1 = *(const bf16x8*)(buf + jl * 512 + ((kt * 64 + lg * 16) ^ ((jl & 7) << 4)));
                c1[0] = __builtin_amdgcn_mfma_f32_16x16x32_bf16(aw1, ax[0][kt], c1[0], 0, 0, 0);
                c1[1] = __builtin_amdgcn_mfma_f32_16x16x32_bf16(aw1, ax[1][kt], c1[1], 0, 0, 0);
            }
            // bias+relu; bias float4 from the LDS holes (broadcast, conflict-free)
            const int j0 = p * 32 + jt * 16 + lg * 4;
            const float4 b4 = *(const float4*)(sm + PE_OFF + ((j0 >> 8) << 11) + ((j0 & 255) << 2));
            #pragma unroll
            for (int mt = 0; mt < 2; ++mt) {
                int m = mt * 16 + l15;
                ushort4 hw;
                hw.x = f2bf(fmaxf(c1[mt][0] + b4.x, 0.f));
                hw.y = f2bf(fmaxf(c1[mt][1] + b4.y, 0.f));
                hw.z = f2bf(fmaxf(c1[mt][2] + b4.z, 0.f));
                hw.w = f2bf(fmaxf(c1[mt][3] + b4.w, 0.f));
                int jb = (jt * 16 + lg * 4) * 2;
                *(ushort4*)(hrb + (((m >> 1) * 128 + (m & 1) * 64 + jb) ^ (((m >> 1) & 7) << 4))) = hw;
            }
        }
        // layer2: Y += hr @ Wa2p^T (A = hr rows m, B = Wa2 cols o), K = 32
        bf16x8 ah[2];
        #pragma unroll
        for (int mt = 0; mt < 2; ++mt) {
            int m = mt * 16 + l15;
            ah[mt] = *(const bf16x8*)(hrb + (((m >> 1) * 128 + (m & 1) * 64 + lg * 16) ^ (((m >> 1) & 7) << 4)));
        }
        #pragma unroll
        for (int ot = 0; ot < 16; ++ot) {
            int o = ot * 16 + l15;
            bf16x8 bW2 = *(const bf16x8*)(buf + 16384 +
                          (((o >> 1) * 128 + (o & 1) * 64 + lg * 16) ^ (((o >> 1) & 7) << 4)));
            Y[0][ot] = __builtin_amdgcn_mfma_f32_16x16x32_bf16(ah[0], bW2, Y[0][ot], 0, 0, 0);
            Y[1][ot] = __builtin_amdgcn_mfma_f32_16x16x32_bf16(ah[1], bW2, Y[1][ot], 0, 0, 0);
        }
        __builtin_amdgcn_s_setprio(0);

        asm volatile("s_waitcnt lgkmcnt(0)" ::: "memory");
        __builtin_amdgcn_s_barrier();          // all waves done reading buf[p&1]
        if (p < 30) {                           // stage(p+2) into the freed buffer
            const char* src = wimg + (size_t)(p + 2) * 32768;
            char* dst = sm + DBUF_OFF + (p & 1) * 32768;
            #pragma unroll
            for (int i = 0; i < 8; ++i)
                gl_lds16(src + i * 4096 + t * 16, dst + i * 4096 + t * 16);
        }
    }

    // ---- softmax over k (k = lg*4+r; registers + shfl) ----
    #pragma unroll
    for (int mt = 0; mt < 2; ++mt) {
        #pragma unroll
        for (int ot = 0; ot < 16; ++ot) {
            float mx = fmaxf(fmaxf(Y[mt][ot][0], Y[mt][ot][1]), fmaxf(Y[mt][ot][2], Y[mt][ot][3]));
            mx = fmaxf(mx, __shfl_xor(mx, 16));
            mx = fmaxf(mx, __shfl_xor(mx, 32));
            float e0 = expf(Y[mt][ot][0] - mx), e1 = expf(Y[mt][ot][1] - mx);
            float e2 = expf(Y[mt][ot][2] - mx), e3 = expf(Y[mt][ot][3] - mx);
            float s = e0 + e1 + e2 + e3;
            s += __shfl_xor(s, 16);
            s += __shfl_xor(s, 32);
            float inv = 1.f / s;
            Y[mt][ot][0] = e0 * inv; Y[mt][ot][1] = e1 * inv;
            Y[mt][ot][2] = e2 * inv; Y[mt][ot][3] = e3 * inv;
        }
    }

    // ---- values -> vB regs via 4 slices; then v GEMM + agg ----
    bf16x8 vB[2][4];
    #pragma unroll 1
    for (int s = 0; s < 4; ++s) {
        const float* vb = values + ((size_t)b * 128 * NN + (size_t)(n0 + 2 * w + nv)) * 16 + kq * 4;
        #pragma unroll
        for (int i = 0; i < 4; ++i) {
            int c = s * 32 + i * 8 + c0;
            float4 v = *(const float4*)(vb + (size_t)c * NN * 16);
            int cl = i * 8 + c0;
            #pragma unroll
            for (int j = 0; j < 4; ++j) {
                int m = nv * 16 + kq * 4 + j;
                float fj = (j == 0) ? v.x : (j == 1) ? v.y : (j == 2) ? v.z : v.w;
                *(unsigned short*)(scw + (((m >> 1) * 128 + (m & 1) * 64 + cl * 2) ^ (((m >> 1) & 7) << 4))) = f2bf(fj);
            }
        }
        #pragma unroll
        for (int mt = 0; mt < 2; ++mt) {
            int m = mt * 16 + l15;
            vB[mt][s] = *(const bf16x8*)(scw + (((m >> 1) * 128 + (m & 1) * 64 + lg * 16) ^ (((m >> 1) & 7) << 4)));
        }
    }

    float aggv[2][16];
    #pragma unroll 4
    for (int ot = 0; ot < 16; ++ot) {
        int o = ot * 16 + l15;
        f32x4 v0 = zf, v1 = zf;
        #pragma unroll
        for (int s = 0; s < 4; ++s) {
            bf16x8 bWv = *(const bf16x8*)(wvp + o * 128 + s * 32 + lg * 8);
            v0 = __builtin_amdgcn_mfma_f32_16x16x32_bf16(vB[0][s], bWv, v0, 0, 0, 0);
            v1 = __builtin_amdgcn_mfma_f32_16x16x32_bf16(vB[1][s], bWv, v1, 0, 0, 0);
        }
        float bvo = bv[o];
        #pragma unroll
        for (int mt = 0; mt < 2; ++mt) {
            f32x4 va = mt ? v1 : v0;
            float s = Y[mt][ot][0] * (va[0] + bvo);
            s = fmaf(Y[mt][ot][1], va[1] + bvo, s);
            s = fmaf(Y[mt][ot][2], va[2] + bvo, s);
            s = fmaf(Y[mt][ot][3], va[3] + bvo, s);
            s += __shfl_xor(s, 16);
            s += __shfl_xor(s, 32);
            aggv[mt][ot] = s + bf2f(*(const unsigned short*)(pew + 1024 + mt * 512 + o * 2));
        }
    }

    __syncthreads();
    // ---- agg hand-off: agg[8nl][256o] bf16 (aliases pe region) ----
    if (lg == 0) {
        #pragma unroll
        for (int mt = 0; mt < 2; ++mt) {
            int nl = 2 * w + mt;
            #pragma unroll
            for (int ot = 0; ot < 16; ++ot) {
                int o = ot * 16 + l15;
                *(unsigned short*)(sm + PE_OFF + ((nl * 512 + o * 2) ^ ((nl & 7) << 4))) = f2bf(aggv[mt][ot]);
            }
        }
    }
    __syncthreads();

    // ---- We GEMM: wave owns 64 oo; A rows = 16 (8 real n) ----
    bf16x8 aa[8];
    #pragma unroll
    for (int kt = 0; kt < 8; ++kt)
        aa[kt] = *(const bf16x8*)(sm + PE_OFF + ((l15 * 512 + kt * 64 + lg * 16) ^ ((l15 & 7) << 4)));
    #pragma unroll
    for (int ot = 0; ot < 4; ++ot) {
        int oo = w * 64 + ot * 16 + l15;
        f32x4 acc = zf;
        #pragma unroll
        for (int kt = 0; kt < 8; ++kt) {
            bf16x8 bWe = *(const bf16x8*)(wep + oo * 256 + kt * 32 + lg * 8);
            acc = __builtin_amdgcn_mfma_f32_16x16x32_bf16(aa[kt], bWe, acc, 0, 0, 0);
        }
        if (lg < 2) {
            float bev = be[oo];
            float4 vv;
            vv.x = acc[0] + bev; vv.y = acc[1] + bev;
            vv.z = acc[2] + bev; vv.w = acc[3] + bev;
            *(float4*)(outp + ((size_t)(b * 256 + oo)) * NN + n0 + lg * 4) = vv;
        }
    }
}

extern "C" void kernel_launch(void* const* d_in, const int* in_sizes, int n_in,
                              void* d_out, int out_size, void* d_ws, size_t ws_size,
                              hipStream_t stream) {
    const float* key    = (const float*)d_in[0];
    const float* values = (const float*)d_in[1];
    const float* pos    = (const float*)d_in[2];
    const float* Wk     = (const float*)d_in[3];
    const float* bk     = (const float*)d_in[4];
    const float* Wq     = (const float*)d_in[5];
    const float* bq     = (const float*)d_in[6];
    const float* Wv     = (const float*)d_in[7];
    const float* bv     = (const float*)d_in[8];
    const float* Wp1    = (const float*)d_in[9];
    const float* bp1    = (const float*)d_in[10];
    const float* pg     = (const float*)d_in[11];
    const float* pb     = (const float*)d_in[12];
    const float* pm     = (const float*)d_in[13];
    const float* pv     = (const float*)d_in[14];
    const float* Wp2    = (const float*)d_in[15];
    const float* bp2    = (const float*)d_in[16];
    const float* Wa1    = (const float*)d_in[17];
    const float* ba1    = (const float*)d_in[18];
    const float* ag     = (const float*)d_in[19];
    const float* ab     = (const float*)d_in[20];
    const float* am     = (const float*)d_in[21];
    const float* av     = (const float*)d_in[22];
    const float* Wa2    = (const float*)d_in[23];
    const float* We     = (const float*)d_in[25];
    const float* be     = (const float*)d_in[26];
    (void)in_sizes; (void)n_in; (void)out_size; (void)ws_size;

    char* ws = (char*)d_ws;

    hipFuncSetAttribute((const void*)pt_main,
                        hipFuncAttributeMaxDynamicSharedMemorySize, LDS_TOTAL);

    hipLaunchKernelGGL(prep_sc, dim3(5), dim3(256), 0, stream,
                       ag, ab, am, av, ba1, Wp1, Wq, bq, bp1, pg, pb, pm, pv, ws);
    hipLaunchKernelGGL(prep_cvt, dim3(640), dim3(256), 0, stream,
                       Wk, Wv, We, Wa1, Wa2, ws);
    hipLaunchKernelGGL(pt_main, dim3(1024), dim3(256), LDS_TOTAL, stream,
                       key, values, pos, Wq, bq, bk, bv, Wp2, bp2, be,
                       (const char*)ws, (float*)d_out);
}

// Round 8
// 589.593 us; speedup vs baseline: 1.3316x; 1.3316x over previous
//
#include <hip/hip_runtime.h>
#include <math.h>

typedef __attribute__((ext_vector_type(8))) short bf16x8;
typedef __attribute__((ext_vector_type(4))) float f32x4;

namespace {
constexpr int NN = 2048;
constexpr float EPSV = 1e-5f;

// ---- workspace layout (bytes) ----
constexpr size_t WK_O   = 0;        // ushort[256*128]  Wk bf16 [o][c]
constexpr size_t WV_O   = 65536;    // ushort[256*128]  Wv bf16 [o][c]
constexpr size_t WEP_O  = 131072;   // ushort[256*256]  We bf16 [o][c]
constexpr size_t B1F_O  = 262144;   // float[1024]      folded bn bias for layer1
constexpr size_t WIMG_O = 266240;   // 32 pair-chunks x 32KB pre-swizzled [Wa1p 16KB | Wa2p 16KB]
constexpr size_t WP1Q_O = 1314816;  // float[64*4]      folded Wp1@Wq (+bias in .w)
constexpr size_t SC_O   = 1315840;  // float[1024]      attn bn scale

// ---- LDS layout (bytes) ----
constexpr int DBUF_OFF = 0;        // 32KB single-buffered pair-chunk image
constexpr int SCW_OFF  = 32768;    // 4 waves x 2KB: key/X/val slices + hr
constexpr int PE_OFF   = 40960;    // 4 waves x 2KB (qpe' + pe); later agg[8][256] bf16
constexpr int B1L_OFF  = 49152;    // float[1024]
constexpr int LDS_TOTAL = 53248;   // 52KB -> 2 blocks/CU proven (round 6: 23% occ)
}

__device__ __forceinline__ unsigned short f2bf(float x) {
    unsigned u = __float_as_uint(x);
    unsigned r = (u + 0x7FFFu + ((u >> 16) & 1u)) >> 16;
    return (unsigned short)r;
}
__device__ __forceinline__ float bf2f(unsigned short h) {
    return __uint_as_float(((unsigned)h) << 16);
}
__device__ __forceinline__ void gl_lds16(const void* gsrc, void* ldst) {
    __builtin_amdgcn_global_load_lds(
        (const __attribute__((address_space(1))) unsigned int*)gsrc,
        (__attribute__((address_space(3))) unsigned int*)ldst,
        16, 0, 0);
}

// ================= prep kernels =================

__global__ void prep_sc(const float* __restrict__ ag,  const float* __restrict__ ab,
                        const float* __restrict__ am,  const float* __restrict__ av,
                        const float* __restrict__ ba1,
                        const float* __restrict__ Wp1, const float* __restrict__ Wq,
                        const float* __restrict__ bq,  const float* __restrict__ bp1,
                        const float* __restrict__ pg,  const float* __restrict__ pb,
                        const float* __restrict__ pm,  const float* __restrict__ pv,
                        char* __restrict__ ws)
{
    const int t = threadIdx.x, blk = blockIdx.x;
    float* b1f  = (float*)(ws + B1F_O);
    float* sc_s = (float*)(ws + SC_O);
    float* wp1q = (float*)(ws + WP1Q_O);
    if (blk < 4) {
        int j = blk * 256 + t;
        float sc = ag[j] * rsqrtf(av[j] + EPSV);
        sc_s[j] = sc;
        b1f[j] = ba1[j] * sc + ab[j] - am[j] * sc;
    } else if (t < 64) {
        int ph = t;
        float scp = pg[ph] * rsqrtf(pv[ph] + EPSV);
        float a0 = 0.f, a1 = 0.f, a2 = 0.f, abv = 0.f;
        for (int c = 0; c < 256; ++c) {
            float wv = Wp1[ph * 256 + c];
            a0 = fmaf(wv, Wq[c * 3 + 0], a0);
            a1 = fmaf(wv, Wq[c * 3 + 1], a1);
            a2 = fmaf(wv, Wq[c * 3 + 2], a2);
            abv = fmaf(wv, bq[c], abv);
        }
        wp1q[ph * 4 + 0] = scp * a0;
        wp1q[ph * 4 + 1] = scp * a1;
        wp1q[ph * 4 + 2] = scp * a2;
        wp1q[ph * 4 + 3] = scp * (abv + bp1[ph]) + (pb[ph] - pm[ph] * scp);
    }
}

// bf16 conversions + pre-swizzled pair-chunk images; 640 blocks x 256
__global__ void prep_cvt(const float* __restrict__ Wk, const float* __restrict__ Wv,
                         const float* __restrict__ We, const float* __restrict__ Wa1,
                         const float* __restrict__ Wa2, char* __restrict__ ws)
{
    const int idx4 = blockIdx.x * 256 + threadIdx.x;
    if (idx4 >= 163840) return;
    const int e0 = idx4 * 4;
    const float* sc_s = (const float*)(ws + SC_O);

    if (e0 < 131072) {   // Wk | Wv | We linear bf16
        const float* src;
        unsigned short* dst;
        if (e0 < 32768)      { src = Wk + e0;          dst = (unsigned short*)(ws + WK_O)  + e0; }
        else if (e0 < 65536) { int e = e0 - 32768; src = Wv + e; dst = (unsigned short*)(ws + WV_O)  + e; }
        else                 { int e = e0 - 65536; src = We + e; dst = (unsigned short*)(ws + WEP_O) + e; }
        float4 v = *(const float4*)src;
        ushort4 o;
        o.x = f2bf(v.x); o.y = f2bf(v.y); o.z = f2bf(v.z); o.w = f2bf(v.w);
        *(ushort4*)dst = o;
    } else if (e0 < 393216) {   // Wa1 folded -> pair image [32j][256c] swz ^((jl&7)<<4)
        int e = e0 - 131072;
        int j = e >> 8, c = e & 255;
        float sc = sc_s[j];
        float4 v = *(const float4*)(Wa1 + e);
        int p = j >> 5, jl = j & 31;
        size_t byte = (size_t)p * 32768 + ((jl * 512 + c * 2) ^ ((jl & 7) << 4));
        ushort4 o;
        o.x = f2bf(v.x * sc); o.y = f2bf(v.y * sc); o.z = f2bf(v.z * sc); o.w = f2bf(v.w * sc);
        *(ushort4*)(ws + WIMG_O + byte) = o;
    } else {                    // Wa2 -> pair image, o-pair rows of 128B, swz ^(((o>>1)&7)<<4)
        int e = e0 - 393216;
        int o = e >> 10, j = e & 1023;
        float4 v = *(const float4*)(Wa2 + e);
        int p = j >> 5, jj = j & 31;
        size_t byte = (size_t)p * 32768 + 16384 +
                      (((o >> 1) * 128 + (o & 1) * 64 + jj * 2) ^ (((o >> 1) & 7) << 4));
        ushort4 ov;
        ov.x = f2bf(v.x); ov.y = f2bf(v.y); ov.z = f2bf(v.z); ov.w = f2bf(v.w);
        *(ushort4*)(ws + WIMG_O + byte) = ov;
    }
}

// ================= main fused kernel =================
// 1024 blocks (4 b x 256 n-tiles of 8), 256 threads = 4 waves; wave owns 32 rows (2 n).
// Register policy: loop live set ~235 VGPR (Y[2][16]=128 + ax[2][8]=64 + temps).
// waves_per_eu(2,2) sets the allocator's occupancy target to exactly 2 waves/EU
// (budget 256 VGPR) -- launch_bounds(256,1) alone let the allocator cap at 200 and
// spill ~1GB of scratch (rounds 4-7 WRITE_SIZE evidence).
__global__ __launch_bounds__(256) __attribute__((amdgpu_waves_per_eu(2, 2)))
void pt_main(const float* __restrict__ key, const float* __restrict__ values,
             const float* __restrict__ pos,
             const float* __restrict__ Wq,  const float* __restrict__ bq,
             const float* __restrict__ bk,  const float* __restrict__ bv,
             const float* __restrict__ Wp2, const float* __restrict__ bp2,
             const float* __restrict__ be,
             const char* __restrict__ ws,
             float* __restrict__ outp)
{
    extern __shared__ char sm[];
    const int t = threadIdx.x;
    const int w = t >> 6, l = t & 63;
    const int l15 = l & 15, lg = l >> 4;
    // XCD-aware swizzle (1024 % 8 == 0 -> simple form is bijective)
    const int wg = (blockIdx.x & 7) * 128 + (blockIdx.x >> 3);
    const int b = wg >> 8;
    const int n0 = (wg & 255) * 8;

    char* scw = sm + SCW_OFF + w * 2048;
    char* pew = sm + PE_OFF + w * 2048;
    float* b1l = (float*)(sm + B1L_OFF);

    const unsigned short* wkp = (const unsigned short*)(ws + WK_O);
    const unsigned short* wvp = (const unsigned short*)(ws + WV_O);
    const unsigned short* wep = (const unsigned short*)(ws + WEP_O);
    const float* b1fp = (const float*)(ws + B1F_O);
    const float* wp1q = (const float*)(ws + WP1Q_O);
    const char* wimg = ws + WIMG_O;

    const f32x4 zf = {0.f, 0.f, 0.f, 0.f};

    // ---- prologue: stage pair-chunk 0 (lands during the whole pre-phase) ----
    #pragma unroll
    for (int i = 0; i < 8; ++i)
        gl_lds16(wimg + i * 4096 + t * 16, sm + DBUF_OFF + i * 4096 + t * 16);

    // ---- b1f -> LDS ----
    #pragma unroll
    for (int i = 0; i < 4; ++i) b1l[t + i * 256] = b1fp[t + i * 256];

    // ---- pe / qpe' phase (wave-local; nl = 2w + {0,1}) ----
    float p_[2][3];
    {
        const float4 wq4 = *(const float4*)(wp1q + l * 4);
        float h1v[2];
        #pragma unroll
        for (int nl = 0; nl < 2; ++nl) {
            int n = n0 + 2 * w + nl;
            p_[nl][0] = pos[(b * 3 + 0) * NN + n];
            p_[nl][1] = pos[(b * 3 + 1) * NN + n];
            p_[nl][2] = pos[(b * 3 + 2) * NN + n];
            h1v[nl] = fmaxf(fmaf(wq4.x, p_[nl][0],
                            fmaf(wq4.y, p_[nl][1],
                            fmaf(wq4.z, p_[nl][2], wq4.w))), 0.f);
        }
        float pacc[2][4];
        #pragma unroll
        for (int nl = 0; nl < 2; ++nl)
            #pragma unroll
            for (int oi = 0; oi < 4; ++oi) pacc[nl][oi] = 0.f;
        #pragma unroll 4
        for (int j4 = 0; j4 < 16; ++j4) {
            float h0[4], h1[4];
            #pragma unroll
            for (int jj = 0; jj < 4; ++jj) {
                h0[jj] = __shfl(h1v[0], j4 * 4 + jj);
                h1[jj] = __shfl(h1v[1], j4 * 4 + jj);
            }
            #pragma unroll
            for (int oi = 0; oi < 4; ++oi) {
                const float4 wv4 = *(const float4*)(Wp2 + (oi * 64 + l) * 64 + j4 * 4);
                pacc[0][oi] = fmaf(wv4.x, h0[0], fmaf(wv4.y, h0[1], fmaf(wv4.z, h0[2], fmaf(wv4.w, h0[3], pacc[0][oi]))));
                pacc[1][oi] = fmaf(wv4.x, h1[0], fmaf(wv4.y, h1[1], fmaf(wv4.z, h1[2], fmaf(wv4.w, h1[3], pacc[1][oi]))));
            }
        }
        #pragma unroll
        for (int oi = 0; oi < 4; ++oi) {
            int o = oi * 64 + l;
            float bp = bp2[o], bko = bk[o], bqo = bq[o];
            float wq0 = Wq[o * 3 + 0], wq1 = Wq[o * 3 + 1], wq2 = Wq[o * 3 + 2];
            #pragma unroll
            for (int nl = 0; nl < 2; ++nl) {
                float pe = pacc[nl][oi] + bp;
                float q  = fmaf(wq0, p_[nl][0], fmaf(wq1, p_[nl][1], fmaf(wq2, p_[nl][2], bqo)));
                *(unsigned short*)(pew + nl * 512 + o * 2)        = f2bf((q + 1.f - bko) * pe);
                *(unsigned short*)(pew + 1024 + nl * 512 + o * 2) = f2bf(pe);
            }
        }
    }

    // ---- kf GEMM in 4 c-slices of 32 through 2KB wave-private scratch ----
    const int kq = l & 3, nv = (l >> 2) & 1, c0 = l >> 3;
    f32x4 kacc[2][16];
    #pragma unroll
    for (int mt = 0; mt < 2; ++mt)
        #pragma unroll
        for (int ot = 0; ot < 16; ++ot) kacc[mt][ot] = zf;

    #pragma unroll 1
    for (int s = 0; s < 4; ++s) {
        const float* kb = key + ((size_t)b * 128 * NN + (size_t)(n0 + 2 * w + nv)) * 16 + kq * 4;
        #pragma unroll
        for (int i = 0; i < 4; ++i) {
            int c = s * 32 + i * 8 + c0;
            float4 v = *(const float4*)(kb + (size_t)c * NN * 16);
            int cl = i * 8 + c0;
            #pragma unroll
            for (int j = 0; j < 4; ++j) {
                int m = nv * 16 + kq * 4 + j;
                float fj = (j == 0) ? v.x : (j == 1) ? v.y : (j == 2) ? v.z : v.w;
                *(unsigned short*)(scw + (((m >> 1) * 128 + (m & 1) * 64 + cl * 2) ^ (((m >> 1) & 7) << 4))) = f2bf(fj);
            }
        }
        bf16x8 kB[2];
        #pragma unroll
        for (int mt = 0; mt < 2; ++mt) {
            int m = mt * 16 + l15;
            kB[mt] = *(const bf16x8*)(scw + (((m >> 1) * 128 + (m & 1) * 64 + lg * 16) ^ (((m >> 1) & 7) << 4)));
        }
        #pragma unroll 4
        for (int ot = 0; ot < 16; ++ot) {
            bf16x8 aW = *(const bf16x8*)(wkp + (ot * 16 + l15) * 128 + s * 32 + lg * 8);
            kacc[0][ot] = __builtin_amdgcn_mfma_f32_16x16x32_bf16(aW, kB[0], kacc[0][ot], 0, 0, 0);
            kacc[1][ot] = __builtin_amdgcn_mfma_f32_16x16x32_bf16(aW, kB[1], kacc[1][ot], 0, 0, 0);
        }
    }

    // ---- X epilogue -> ax registers, 8 o-slices of 32 through scratch ----
    bf16x8 ax[2][8];
    #pragma unroll 1
    for (int x = 0; x < 8; ++x) {
        #pragma unroll
        for (int mt = 0; mt < 2; ++mt) {
            const int m = mt * 16 + l15;
            #pragma unroll
            for (int oi = 0; oi < 2; ++oi) {
                int ot = x * 2 + oi;
                int o0 = ot * 16 + lg * 4;
                ushort4 qv  = *(const ushort4*)(pew + mt * 512 + o0 * 2);
                ushort4 pv4 = *(const ushort4*)(pew + 1024 + mt * 512 + o0 * 2);
                ushort4 pk;
                pk.x = f2bf(bf2f(qv.x) - kacc[mt][ot][0] * bf2f(pv4.x));
                pk.y = f2bf(bf2f(qv.y) - kacc[mt][ot][1] * bf2f(pv4.y));
                pk.z = f2bf(bf2f(qv.z) - kacc[mt][ot][2] * bf2f(pv4.z));
                pk.w = f2bf(bf2f(qv.w) - kacc[mt][ot][3] * bf2f(pv4.w));
                int ol = oi * 16 + lg * 4;
                *(ushort4*)(scw + (((m >> 1) * 128 + (m & 1) * 64 + ol * 2) ^ (((m >> 1) & 7) << 4))) = pk;
            }
        }
        #pragma unroll
        for (int mt = 0; mt < 2; ++mt) {
            int m = mt * 16 + l15;
            ax[mt][x] = *(const bf16x8*)(scw + (((m >> 1) * 128 + (m & 1) * 64 + lg * 16) ^ (((m >> 1) & 7) << 4)));
        }
    }

    // ---- attn MLP: 32 pair-chunks of 32 j; single-buffered gl_lds image staging ----
    f32x4 Y[2][16];
    #pragma unroll
    for (int mt = 0; mt < 2; ++mt)
        #pragma unroll
        for (int ot = 0; ot < 16; ++ot) Y[mt][ot] = zf;

    char* hrb = scw;  // wave-private hr [32m][32j] bf16, pair-rows 128B, swz

    #pragma unroll 1
    for (int p = 0; p < 32; ++p) {
        asm volatile("s_waitcnt vmcnt(0) lgkmcnt(0)" ::: "memory");
        __builtin_amdgcn_s_barrier();          // image p ready for all waves
        __builtin_amdgcn_sched_barrier(0);

        // layer1: C[j][m] = Wa1p @ X   (A = Wa1 rows j, B = ax cols m)
        __builtin_amdgcn_s_setprio(1);
        #pragma unroll
        for (int jt = 0; jt < 2; ++jt) {
            const int jl = jt * 16 + l15;
            f32x4 c1[2];
            c1[0] = zf; c1[1] = zf;
            #pragma unroll
            for (int kt = 0; kt < 8; ++kt) {
                bf16x8 aw1 = *(const bf16x8*)(sm + DBUF_OFF + jl * 512 + ((kt * 64 + lg * 16) ^ ((jl & 7) << 4)));
                c1[0] = __builtin_amdgcn_mfma_f32_16x16x32_bf16(aw1, ax[0][kt], c1[0], 0, 0, 0);
                c1[1] = __builtin_amdgcn_mfma_f32_16x16x32_bf16(aw1, ax[1][kt], c1[1], 0, 0, 0);
            }
            // bias+relu; lane holds 4 consecutive j for col m=l15 -> packed b64 write
            const float4 b4 = *(const float4*)(b1l + p * 32 + jt * 16 + lg * 4);
            #pragma unroll
            for (int mt = 0; mt < 2; ++mt) {
                int m = mt * 16 + l15;
                ushort4 hw;
                hw.x = f2bf(fmaxf(c1[mt][0] + b4.x, 0.f));
                hw.y = f2bf(fmaxf(c1[mt][1] + b4.y, 0.f));
                hw.z = f2bf(fmaxf(c1[mt][2] + b4.z, 0.f));
                hw.w = f2bf(fmaxf(c1[mt][3] + b4.w, 0.f));
                int jb = (jt * 16 + lg * 4) * 2;
                *(ushort4*)(hrb + (((m >> 1) * 128 + (m & 1) * 64 + jb) ^ (((m >> 1) & 7) << 4))) = hw;
            }
        }
        // layer2: Y += hr @ Wa2p^T (A = hr rows m, B = Wa2 cols o), K = 32
        bf16x8 ah[2];
        #pragma unroll
        for (int mt = 0; mt < 2; ++mt) {
            int m = mt * 16 + l15;
            ah[mt] = *(const bf16x8*)(hrb + (((m >> 1) * 128 + (m & 1) * 64 + lg * 16) ^ (((m >> 1) & 7) << 4)));
        }
        #pragma unroll
        for (int ot = 0; ot < 16; ++ot) {
            int o = ot * 16 + l15;
            bf16x8 bW2 = *(const bf16x8*)(sm + DBUF_OFF + 16384 +
                          (((o >> 1) * 128 + (o & 1) * 64 + lg * 16) ^ (((o >> 1) & 7) << 4)));
            Y[0][ot] = __builtin_amdgcn_mfma_f32_16x16x32_bf16(ah[0], bW2, Y[0][ot], 0, 0, 0);
            Y[1][ot] = __builtin_amdgcn_mfma_f32_16x16x32_bf16(ah[1], bW2, Y[1][ot], 0, 0, 0);
        }
        __builtin_amdgcn_s_setprio(0);

        asm volatile("s_waitcnt lgkmcnt(0)" ::: "memory");
        __builtin_amdgcn_s_barrier();          // all waves done reading image p
        if (p < 31) {
            const char* src = wimg + (size_t)(p + 1) * 32768;
            #pragma unroll
            for (int i = 0; i < 8; ++i)
                gl_lds16(src + i * 4096 + t * 16, sm + DBUF_OFF + i * 4096 + t * 16);
        }
    }

    // ---- softmax over k (k = lg*4+r; registers + shfl) ----
    #pragma unroll
    for (int mt = 0; mt < 2; ++mt) {
        #pragma unroll
        for (int ot = 0; ot < 16; ++ot) {
            float mx = fmaxf(fmaxf(Y[mt][ot][0], Y[mt][ot][1]), fmaxf(Y[mt][ot][2], Y[mt][ot][3]));
            mx = fmaxf(mx, __shfl_xor(mx, 16));
            mx = fmaxf(mx, __shfl_xor(mx, 32));
            float e0 = expf(Y[mt][ot][0] - mx), e1 = expf(Y[mt][ot][1] - mx);
            float e2 = expf(Y[mt][ot][2] - mx), e3 = expf(Y[mt][ot][3] - mx);
            float s = e0 + e1 + e2 + e3;
            s += __shfl_xor(s, 16);
            s += __shfl_xor(s, 32);
            float inv = 1.f / s;
            Y[mt][ot][0] = e0 * inv; Y[mt][ot][1] = e1 * inv;
            Y[mt][ot][2] = e2 * inv; Y[mt][ot][3] = e3 * inv;
        }
    }

    // ---- values -> vB regs via 4 slices; then v GEMM + agg ----
    bf16x8 vB[2][4];
    #pragma unroll 1
    for (int s = 0; s < 4; ++s) {
        const float* vb = values + ((size_t)b * 128 * NN + (size_t)(n0 + 2 * w + nv)) * 16 + kq * 4;
        #pragma unroll
        for (int i = 0; i < 4; ++i) {
            int c = s * 32 + i * 8 + c0;
            float4 v = *(const float4*)(vb + (size_t)c * NN * 16);
            int cl = i * 8 + c0;
            #pragma unroll
            for (int j = 0; j < 4; ++j) {
                int m = nv * 16 + kq * 4 + j;
                float fj = (j == 0) ? v.x : (j == 1) ? v.y : (j == 2) ? v.z : v.w;
                *(unsigned short*)(scw + (((m >> 1) * 128 + (m & 1) * 64 + cl * 2) ^ (((m >> 1) & 7) << 4))) = f2bf(fj);
            }
        }
        #pragma unroll
        for (int mt = 0; mt < 2; ++mt) {
            int m = mt * 16 + l15;
            vB[mt][s] = *(const bf16x8*)(scw + (((m >> 1) * 128 + (m & 1) * 64 + lg * 16) ^ (((m >> 1) & 7) << 4)));
        }
    }

    float aggv[2][16];
    #pragma unroll 4
    for (int ot = 0; ot < 16; ++ot) {
        int o = ot * 16 + l15;
        f32x4 v0 = zf, v1 = zf;
        #pragma unroll
        for (int s = 0; s < 4; ++s) {
            bf16x8 bWv = *(const bf16x8*)(wvp + o * 128 + s * 32 + lg * 8);
            v0 = __builtin_amdgcn_mfma_f32_16x16x32_bf16(vB[0][s], bWv, v0, 0, 0, 0);
            v1 = __builtin_amdgcn_mfma_f32_16x16x32_bf16(vB[1][s], bWv, v1, 0, 0, 0);
        }
        float bvo = bv[o];
        #pragma unroll
        for (int mt = 0; mt < 2; ++mt) {
            f32x4 va = mt ? v1 : v0;
            float s = Y[mt][ot][0] * (va[0] + bvo);
            s = fmaf(Y[mt][ot][1], va[1] + bvo, s);
            s = fmaf(Y[mt][ot][2], va[2] + bvo, s);
            s = fmaf(Y[mt][ot][3], va[3] + bvo, s);
            s += __shfl_xor(s, 16);
            s += __shfl_xor(s, 32);
            aggv[mt][ot] = s + bf2f(*(const unsigned short*)(pew + 1024 + mt * 512 + o * 2));
        }
    }

    __syncthreads();
    // ---- agg hand-off: agg[8nl][256o] bf16 (aliases pe region) ----
    if (lg == 0) {
        #pragma unroll
        for (int mt = 0; mt < 2; ++mt) {
            int nl = 2 * w + mt;
            #pragma unroll
            for (int ot = 0; ot < 16; ++ot) {
                int o = ot * 16 + l15;
                *(unsigned short*)(sm + PE_OFF + ((nl * 512 + o * 2) ^ ((nl & 7) << 4))) = f2bf(aggv[mt][ot]);
            }
        }
    }
    __syncthreads();

    // ---- We GEMM: wave owns 64 oo; A rows = 16 (8 real n) ----
    bf16x8 aa[8];
    #pragma unroll
    for (int kt = 0; kt < 8; ++kt)
        aa[kt] = *(const bf16x8*)(sm + PE_OFF + ((l15 * 512 + kt * 64 + lg * 16) ^ ((l15 & 7) << 4)));
    #pragma unroll
    for (int ot = 0; ot < 4; ++ot) {
        int oo = w * 64 + ot * 16 + l15;
        f32x4 acc = zf;
        #pragma unroll
        for (int kt = 0; kt < 8; ++kt) {
            bf16x8 bWe = *(const bf16x8*)(wep + oo * 256 + kt * 32 + lg * 8);
            acc = __builtin_amdgcn_mfma_f32_16x16x32_bf16(aa[kt], bWe, acc, 0, 0, 0);
        }
        if (lg < 2) {
            float bev = be[oo];
            float4 vv;
            vv.x = acc[0] + bev; vv.y = acc[1] + bev;
            vv.z = acc[2] + bev; vv.w = acc[3] + bev;
            *(float4*)(outp + ((size_t)(b * 256 + oo)) * NN + n0 + lg * 4) = vv;
        }
    }
}

extern "C" void kernel_launch(void* const* d_in, const int* in_sizes, int n_in,
                              void* d_out, int out_size, void* d_ws, size_t ws_size,
                              hipStream_t stream) {
    const float* key    = (const float*)d_in[0];
    const float* values = (const float*)d_in[1];
    const float* pos    = (const float*)d_in[2];
    const float* Wk     = (const float*)d_in[3];
    const float* bk     = (const float*)d_in[4];
    const float* Wq     = (const float*)d_in[5];
    const float* bq     = (const float*)d_in[6];
    const float* Wv     = (const float*)d_in[7];
    const float* bv     = (const float*)d_in[8];
    const float* Wp1    = (const float*)d_in[9];
    const float* bp1    = (const float*)d_in[10];
    const float* pg     = (const float*)d_in[11];
    const float* pb     = (const float*)d_in[12];
    const float* pm     = (const float*)d_in[13];
    const float* pv     = (const float*)d_in[14];
    const float* Wp2    = (const float*)d_in[15];
    const float* bp2    = (const float*)d_in[16];
    const float* Wa1    = (const float*)d_in[17];
    const float* ba1    = (const float*)d_in[18];
    const float* ag     = (const float*)d_in[19];
    const float* ab     = (const float*)d_in[20];
    const float* am     = (const float*)d_in[21];
    const float* av     = (const float*)d_in[22];
    const float* Wa2    = (const float*)d_in[23];
    const float* We     = (const float*)d_in[25];
    const float* be     = (const float*)d_in[26];
    (void)in_sizes; (void)n_in; (void)out_size; (void)ws_size;

    char* ws = (char*)d_ws;

    hipFuncSetAttribute((const void*)pt_main,
                        hipFuncAttributeMaxDynamicSharedMemorySize, LDS_TOTAL);

    hipLaunchKernelGGL(prep_sc, dim3(5), dim3(256), 0, stream,
                       ag, ab, am, av, ba1, Wp1, Wq, bq, bp1, pg, pb, pm, pv, ws);
    hipLaunchKernelGGL(prep_cvt, dim3(640), dim3(256), 0, stream,
                       Wk, Wv, We, Wa1, Wa2, ws);
    hipLaunchKernelGGL(pt_main, dim3(1024), dim3(256), LDS_TOTAL, stream,
                       key, values, pos, Wq, bq, bk, bv, Wp2, bp2, be,
                       (const char*)ws, (float*)d_out);
}